// Round 5
// baseline (43.387 us; speedup 1.0000x reference)
//
#include <hip/hip_runtime.h>
#include <math.h>

#define IMG_H  384
#define IMG_W  384
#define IMG_HW (IMG_H * IMG_W)
#define NB     4
#define NC     3
#define NK     48
#define ND     6           /* dilations */

struct PosAdd { float v[NK]; };

/* 4-way tap split: slot = lane>>4 handles tap pair {2s, 2s+1} of every dilation.
   tap positions (row,col) in units of d:
     0:(-1,-1) 1:(-1,0) 2:(-1,+1) 3:(0,-1) 4:(0,+1) 5:(+1,-1) 6:(+1,0) 7:(+1,+1)
   slot0 -> taps {0,1}, slot1 -> {2,3}, slot2 -> {4,5}, slot3 -> {6,7} */

__global__ __launch_bounds__(256, 8) void LLA_41412074668179_kernel(
    const float* __restrict__ imgs, float* __restrict__ out, PosAdd pa)
{
    const int tid  = threadIdx.x;
    const int lane = tid & 63;
    const int slot = lane >> 4;            // 0..3
    const bool s0 = slot & 1;
    const bool s1 = (slot >> 1) & 1;

    // XCD-chunked swizzle: 9216 blocks = 8 XCDs x 1152 contiguous chunks
    const int lb = (blockIdx.x & 7) * 1152 + (blockIdx.x >> 3);

    // 16 consecutive pixels per quarter-wave; all 4 slots cover the same 16 px.
    // 16 | 384 => a 16-lane group never straddles a row.
    const int px = lb * 64 + (tid >> 6) * 16 + (lane & 15);
    const int w  = px % IMG_W;
    const int hb = px / IMG_W;
    const int h  = hb % IMG_H;
    const int b  = hb / IMG_H;
    const int r0 = h * IMG_W;

    const int DIL[ND] = {1, 2, 4, 8, 12, 24};

    // branchless clamped offsets for my 2 taps of each dilation
    int offU[ND], offV[ND];
#pragma unroll
    for (int di = 0; di < ND; ++di) {
        const int d  = DIL[di];
        const int rm = max(h - d, 0) * IMG_W;
        const int rp = min(h + d, IMG_H - 1) * IMG_W;
        const int cm = max(w - d, 0);
        const int cp = min(w + d, IMG_W - 1);
        const int rowU = s1 ? (s0 ? rp : r0) : rm;
        const int rowV = s1 ? rp : (s0 ? r0 : rm);
        const int colU = s1 ? (s0 ? w  : cp) : (s0 ? cp : cm);
        const int colV = s1 ? (s0 ? cp : cm) : (s0 ? cm : w);
        offU[di] = rowU + colU;
        offV[di] = rowV + colV;
    }
    const int xoff = r0 + w;

    float accU[ND], accV[ND];
#pragma unroll
    for (int di = 0; di < ND; ++di) { accU[di] = 0.0f; accV[di] = 0.0f; }

#pragma unroll
    for (int c = 0; c < NC; ++c) {
        const float* __restrict__ pc = imgs + (b * NC + c) * IMG_HW;

        const float x = pc[xoff];
        float u[ND], v[ND];
#pragma unroll
        for (int di = 0; di < ND; ++di) {
            u[di] = pc[offU[di]];
            v[di] = pc[offV[di]];
        }

        // partial stats over my 12 taps; combine across 4 slots -> all 48
        float s  = 0.0f, ss = 0.0f;
        float s2 = 0.0f, ss2 = 0.0f;
#pragma unroll
        for (int di = 0; di < ND; di += 2) {
            s   += u[di]   + v[di];
            s2  += u[di+1] + v[di+1];
            ss  = fmaf(u[di],   u[di],   fmaf(v[di],   v[di],   ss));
            ss2 = fmaf(u[di+1], u[di+1], fmaf(v[di+1], v[di+1], ss2));
        }
        s  += s2;
        ss += ss2;
        s  += __shfl_xor(s,  16);
        s  += __shfl_xor(s,  32);
        ss += __shfl_xor(ss, 16);
        ss += __shfl_xor(ss, 32);

        const float mean = s * (1.0f / 48.0f);
        const float var  = fmaxf((ss - s * mean) * (1.0f / 47.0f), 0.0f);
        const float scl  = __builtin_amdgcn_rcpf(
                               fmaf(__builtin_amdgcn_sqrtf(var), 0.3f, 3.0e-9f));
        const float xs = x * scl;

#pragma unroll
        for (int di = 0; di < ND; ++di) {
            const float du = fmaf(u[di], scl, -xs);
            const float dv = fmaf(v[di], scl, -xs);
            accU[di] = fmaf(du, du, accU[di]);
            accV[di] = fmaf(dv, dv, accV[di]);
        }
    }

    // softmax over all 48: max(aff) == min(acc); cross-slot via shfl
    float m0 = fminf(accU[0], accV[0]), m1 = fminf(accU[1], accV[1]);
    float m2 = fminf(accU[2], accV[2]), m3 = fminf(accU[3], accV[3]);
    m0 = fminf(m0, fminf(accU[4], accV[4]));
    m1 = fminf(m1, fminf(accU[5], accV[5]));
    float mn = fminf(fminf(m0, m1), fminf(m2, m3));
    mn = fminf(mn, __shfl_xor(mn, 16));
    mn = fminf(mn, __shfl_xor(mn, 32));

    const float SC   = (1.0f / 3.0f) * 1.44269504f;   // /3 then ln->log2
    const float mnSC = mn * SC;
    float e0 = 0.0f, e1 = 0.0f;
#pragma unroll
    for (int di = 0; di < ND; ++di) {
        accU[di] = __builtin_amdgcn_exp2f(fmaf(accU[di], -SC, mnSC));
        accV[di] = __builtin_amdgcn_exp2f(fmaf(accV[di], -SC, mnSC));
        e0 += accU[di];
        e1 += accV[di];
    }
    float se = e0 + e1;
    se += __shfl_xor(se, 16);
    se += __shfl_xor(se, 32);
    const float inv = __builtin_amdgcn_rcpf(se);

    // my planes: k = di*8 + 2*slot (+1); branchless pos-add selection (no dynamic idx)
    float* __restrict__ ob = out + (size_t)(b * NK + 2 * slot) * IMG_HW + xoff;
#pragma unroll
    for (int di = 0; di < ND; ++di) {
        const float paU = s1 ? (s0 ? pa.v[di*8+6] : pa.v[di*8+4])
                             : (s0 ? pa.v[di*8+2] : pa.v[di*8+0]);
        const float paV = s1 ? (s0 ? pa.v[di*8+7] : pa.v[di*8+5])
                             : (s0 ? pa.v[di*8+3] : pa.v[di*8+1]);
        __builtin_nontemporal_store(fmaf(accU[di], inv, paU),
                                    ob + (size_t)(di * 8)     * IMG_HW);
        __builtin_nontemporal_store(fmaf(accV[di], inv, paV),
                                    ob + (size_t)(di * 8 + 1) * IMG_HW);
    }
}

static void compute_pos_add(float* out48)
{
    const int DIL[6] = {1, 2, 4, 8, 12, 24};
    const double SQ2 = 1.4142135623730951;
    const double diag[8] = {SQ2, 1.0, SQ2, 1.0, 1.0, SQ2, 1.0, SQ2};

    double pos[NK];
    for (int di = 0; di < 6; ++di)
        for (int tp = 0; tp < 8; ++tp)
            pos[di * 8 + tp] = (double)((float)(diag[tp] * DIL[di]));  // match fp32 concat

    double s = 0.0;
    for (int k = 0; k < NK; ++k) s += pos[k];
    const double m = s / NK;
    double v = 0.0;
    for (int k = 0; k < NK; ++k) { const double d = pos[k] - m; v += d * d; }
    v /= (NK - 1);
    const double stdv = sqrt(v);

    double aff[NK];
    double mx = -1e300;
    for (int k = 0; k < NK; ++k) {
        const double q = pos[k] / ((stdv + 1e-8) * 0.3);
        aff[k] = -(q * q);
        if (aff[k] > mx) mx = aff[k];
    }
    double se = 0.0;
    for (int k = 0; k < NK; ++k) { aff[k] = exp(aff[k] - mx); se += aff[k]; }
    for (int k = 0; k < NK; ++k) out48[k] = (float)(0.01 * aff[k] / se);
}

extern "C" void kernel_launch(void* const* d_in, const int* in_sizes, int n_in,
                              void* d_out, int out_size, void* d_ws, size_t ws_size,
                              hipStream_t stream)
{
    const float* imgs = (const float*)d_in[0];
    float* out = (float*)d_out;

    PosAdd pa;
    compute_pos_add(pa.v);

    // 4 thread-slots per pixel (k-split across quarter-waves), 1 pixel per thread
    const int blocks = (NB * IMG_H * IMG_W * 4) / 256;   // 9216
    LLA_41412074668179_kernel<<<blocks, 256, 0, stream>>>(imgs, out, pa);
}